// Round 1
// baseline (223.369 us; speedup 1.0000x reference)
//
#include <hip/hip_runtime.h>
#include <stdint.h>

// DynamicMaxPool: per-column k-max pooling with order preservation.
// x: [B=16, T=4096, C=256] f32. For each (b,c): keep the k largest of the
// first pr rows (ties -> lower row index first, matching stable argsort),
// compacted to rows 0..k-1 in original row order; rows k..T-1 are zero.
// Output 1: k per batch (float32).

constexpr int T_ROWS = 4096;
constexpr int C_COLS = 256;
constexpr int NBATCH = 16;
constexpr int BLOCK  = 256;
constexpr int EPT    = T_ROWS / BLOCK;   // 16 rows per thread
constexpr int NCOL   = 4;                // columns per block
constexpr int NSUB   = 8;                // histogram sub-counters per bin
constexpr int NGROUP = C_COLS / NCOL;    // 64 column-groups per batch

__global__ __launch_bounds__(BLOCK)
void kmax_pool_kernel(const float* __restrict__ x,
                      const int*   __restrict__ lengths,
                      const int*   __restrict__ pool_ranges,
                      const int*   __restrict__ p_top_k,
                      const int*   __restrict__ p_layer,
                      const int*   __restrict__ p_total,
                      float*       __restrict__ out)
{
    __shared__ uint32_t hist[256 * NSUB];     // [bin][sub]
    __shared__ uint32_t scanbuf[BLOCK];
    __shared__ uint32_t wsum[BLOCK / 64];
    __shared__ uint32_t sh_sel, sh_rem;

    const int bid  = blockIdx.x;
    const int b    = bid / NGROUP;
    const int cg   = bid % NGROUP;
    const int c0   = cg * NCOL;
    const int t    = threadIdx.x;
    const int lane = t & 63;
    const int wid  = t >> 6;

    int pr = pool_ranges[b];
    pr = pr < 0 ? 0 : (pr > T_ROWS ? T_ROWS : pr);
    const int len   = lengths[b];
    const int top_k = p_top_k[0];
    const int tot   = p_total[0];
    const int num   = tot - p_layer[0];
    int k = (num * len + tot - 1) / tot;   // ceil, positive ints
    if (k < top_k) k = top_k;
    if (k > pr)    k = pr;                 // reference clips by pool_ranges

    const int base_row = t * EPT;
    int nv = pr - base_row;                // valid rows owned by this thread
    nv = nv < 0 ? 0 : (nv > EPT ? EPT : nv);

    const size_t colbase = (size_t)b * T_ROWS * C_COLS + (size_t)c0;

    // ---- Load once: 16 rows x 4 cols per thread, as sortable uints ----
    uint32_t u[EPT][NCOL];
    #pragma unroll
    for (int i = 0; i < EPT; ++i) {
        if (i < nv) {
            const float4 v = *reinterpret_cast<const float4*>(
                x + colbase + (size_t)(base_row + i) * C_COLS);
            const uint32_t w[4] = {__float_as_uint(v.x), __float_as_uint(v.y),
                                   __float_as_uint(v.z), __float_as_uint(v.w)};
            #pragma unroll
            for (int j = 0; j < NCOL; ++j)
                u[i][j] = w[j] ^ ((w[j] >> 31) ? 0xFFFFFFFFu : 0x80000000u);
        } else {
            #pragma unroll
            for (int j = 0; j < NCOL; ++j) u[i][j] = 0u;
        }
    }

    uint32_t thr[NCOL], tneed[NCOL];

    if (k > 0) {
        // ---- Radix-select the k-th largest, per column ----
        #pragma unroll
        for (int j = 0; j < NCOL; ++j) {
            uint32_t prefix = 0u, pmask = 0u, rem = (uint32_t)k;
            for (int pass = 0; pass < 4; ++pass) {
                const int shift = 24 - 8 * pass;
                #pragma unroll
                for (int z = 0; z < NSUB; ++z) hist[t * NSUB + z] = 0u;
                __syncthreads();
                const uint32_t sub = (uint32_t)(t & (NSUB - 1));
                #pragma unroll
                for (int i = 0; i < EPT; ++i) {
                    if (i < nv) {
                        const uint32_t ui = u[i][j];
                        if ((ui & pmask) == prefix)
                            atomicAdd(&hist[((ui >> shift) & 255u) * NSUB + sub], 1u);
                    }
                }
                __syncthreads();
                uint32_t cb = 0;
                #pragma unroll
                for (int z = 0; z < NSUB; ++z) cb += hist[t * NSUB + z];
                scanbuf[t] = cb;    // scanbuf[bin] = count
                __syncthreads();
                if (wid == 0) {
                    // lane l owns bins 255-4l .. 252-4l (descending)
                    uint32_t c4[4], loc[4], s = 0;
                    #pragma unroll
                    for (int q = 0; q < 4; ++q) {
                        c4[q]  = scanbuf[255 - 4 * lane - q];
                        loc[q] = s;
                        s += c4[q];
                    }
                    uint32_t incl = s;   // inclusive scan over lanes
                    #pragma unroll
                    for (int off = 1; off < 64; off <<= 1) {
                        const uint32_t nb = __shfl_up(incl, (unsigned)off, 64);
                        if (lane >= off) incl += nb;
                    }
                    const uint32_t gexcl = incl - s;
                    #pragma unroll
                    for (int q = 0; q < 4; ++q) {
                        const uint32_t sbb = gexcl + loc[q]; // #elems in higher bins
                        if (sbb < rem && sbb + c4[q] >= rem) {   // unique crossing
                            sh_sel = (uint32_t)(255 - 4 * lane - q);
                            sh_rem = rem - sbb;
                        }
                    }
                }
                __syncthreads();
                prefix |= sh_sel << shift;
                pmask  |= 0xFFu << shift;
                rem = sh_rem;
                __syncthreads();   // protect sh_*/hist reuse
            }
            thr[j]   = prefix;   // exact k-th largest value (as sortable uint)
            tneed[j] = rem;      // how many ties (==thr) to keep, in row order
        }

        // ---- Keep + compacted positions + write ----
        #pragma unroll
        for (int j = 0; j < NCOL; ++j) {
            const uint32_t th = thr[j], tn = tneed[j];
            uint32_t gt = 0, eq = 0;
            #pragma unroll
            for (int i = 0; i < EPT; ++i) {
                if (i < nv) {
                    gt += (u[i][j] > th) ? 1u : 0u;
                    eq += (u[i][j] == th) ? 1u : 0u;
                }
            }
            const uint32_t mine = (gt << 16) | eq;  // totals <= 4096, no carry
            uint32_t incl = mine;
            #pragma unroll
            for (int off = 1; off < 64; off <<= 1) {
                const uint32_t nb = __shfl_up(incl, (unsigned)off, 64);
                if (lane >= off) incl += nb;
            }
            if (lane == 63) wsum[wid] = incl;
            __syncthreads();
            uint32_t woff = 0;
            for (int w = 0; w < wid; ++w) woff += wsum[w];
            const uint32_t excl = incl + woff - mine;
            uint32_t g = excl >> 16;       // kept-gt strictly before my rows
            uint32_t e = excl & 0xFFFFu;   // eq strictly before my rows
            #pragma unroll
            for (int i = 0; i < EPT; ++i) {
                if (i < nv) {
                    const uint32_t ui = u[i][j];
                    const bool isgt = ui > th;
                    const bool iseq = (ui == th);
                    if (isgt || (iseq && e < tn)) {
                        const uint32_t pos = g + (e < tn ? e : tn);
                        const uint32_t bits =
                            ui ^ ((ui >> 31) ? 0x80000000u : 0xFFFFFFFFu);
                        out[colbase + (size_t)pos * C_COLS + (size_t)j] =
                            __uint_as_float(bits);
                    }
                    g += isgt ? 1u : 0u;
                    e += iseq ? 1u : 0u;
                }
            }
            __syncthreads();   // wsum/scan reuse
        }
    }

    // ---- Zero-fill rows [k, T) (covers invalid region too, k <= pr) ----
    for (int r = k + t; r < T_ROWS; r += BLOCK) {
        const float4 z = make_float4(0.f, 0.f, 0.f, 0.f);
        *reinterpret_cast<float4*>(out + colbase + (size_t)r * C_COLS) = z;
    }

    // ---- Output 1: pool_result_ranges (k per batch), as float32 ----
    if (cg == 0 && t == 0)
        out[(size_t)NBATCH * T_ROWS * C_COLS + (size_t)b] = (float)k;
}

extern "C" void kernel_launch(void* const* d_in, const int* in_sizes, int n_in,
                              void* d_out, int out_size, void* d_ws, size_t ws_size,
                              hipStream_t stream)
{
    const float* x            = (const float*)d_in[0];
    const int*   lengths      = (const int*)d_in[1];
    const int*   pool_ranges  = (const int*)d_in[2];
    const int*   top_k        = (const int*)d_in[3];
    const int*   layer        = (const int*)d_in[4];
    const int*   total_layers = (const int*)d_in[5];
    float*       out          = (float*)d_out;

    dim3 grid(NBATCH * NGROUP);   // 16 * 64 = 1024 blocks
    dim3 block(BLOCK);
    hipLaunchKernelGGL(kmax_pool_kernel, grid, block, 0, stream,
                       x, lengths, pool_ranges, top_k, layer, total_layers, out);
}

// Round 2
// 118.961 us; speedup vs baseline: 1.8777x; 1.8777x over previous
//
#include <hip/hip_runtime.h>
#include <stdint.h>

// DynamicMaxPool: per-column k-max pooling with order preservation.
// x: [B=16, T=4096, C=256] f32. For each (b,c): keep the k largest of the
// first pr rows (ties -> lower row index, matching stable argsort), compacted
// to rows 0..k-1 in original row order; rows k..T-1 zero. k is per-BATCH, so
// the output is a dense [k,C] slab + zeros -> two-phase: dense select into ws
// (block-local layout, fully-dirtied lines), then coalesced transpose+zerofill.
// Output 1: k per batch (float32).

constexpr int T_ROWS = 4096;
constexpr int C_COLS = 256;
constexpr int NBATCH = 16;
constexpr int BLOCK  = 256;
constexpr int EPT    = T_ROWS / BLOCK;   // 16 rows per thread
constexpr int NCOL   = 4;                // columns per select-block
constexpr int NSUB   = 8;                // histogram sub-counters per bin
constexpr int NGROUP = C_COLS / NCOL;    // 64 column-groups per batch
constexpr int NBLK   = NBATCH * NGROUP;  // 1024 select blocks
constexpr size_t NTOT = (size_t)NBATCH * T_ROWS * C_COLS;

__device__ __forceinline__ int compute_k(const int* lengths, const int* pool_ranges,
                                         const int* p_top_k, const int* p_layer,
                                         const int* p_total, int b, int* pr_out)
{
    int pr = pool_ranges[b];
    pr = pr < 0 ? 0 : (pr > T_ROWS ? T_ROWS : pr);
    const int len   = lengths[b];
    const int top_k = p_top_k[0];
    const int tot   = p_total[0];
    const int num   = tot - p_layer[0];
    int k = (num * len + tot - 1) / tot;   // ceil, positive ints
    if (k < top_k) k = top_k;
    if (k > pr)    k = pr;
    *pr_out = pr;
    return k;
}

// MODE 0: write dense per-block slab into ws (K2 transposes). MODE 1: direct
// scattered writes to out + zero-fill (fallback when ws too small).
template<int MODE>
__global__ __launch_bounds__(BLOCK)
void kmax_select_kernel(const float* __restrict__ x,
                        const int*   __restrict__ lengths,
                        const int*   __restrict__ pool_ranges,
                        const int*   __restrict__ p_top_k,
                        const int*   __restrict__ p_layer,
                        const int*   __restrict__ p_total,
                        float*       __restrict__ out,
                        float*       __restrict__ ws)
{
    __shared__ uint32_t hist[256 * NSUB];     // [bin][sub]
    __shared__ uint32_t scanbuf[BLOCK];
    __shared__ uint32_t wsum[BLOCK / 64];
    __shared__ uint32_t sh_sel, sh_rem;

    // XCD-chunked swizzle: adjacent lin (adjacent cg) -> same XCD, adjacent
    // issue slot -> 4 blocks sharing each 64B x/out line co-reside in one L2.
    const int bid  = blockIdx.x;
    const int lin  = (bid & 7) * (NBLK / 8) + (bid >> 3);
    const int b    = lin / NGROUP;
    const int cg   = lin % NGROUP;
    const int c0   = cg * NCOL;
    const int t    = threadIdx.x;
    const int lane = t & 63;
    const int wid  = t >> 6;

    int pr;
    const int k = compute_k(lengths, pool_ranges, p_top_k, p_layer, p_total, b, &pr);

    const int base_row = t * EPT;
    int nv = pr - base_row;                // valid rows owned by this thread
    nv = nv < 0 ? 0 : (nv > EPT ? EPT : nv);

    const size_t colbase = (size_t)b * T_ROWS * C_COLS + (size_t)c0;

    // ---- Load once: 16 rows x 4 cols per thread, as sortable uints ----
    uint32_t u[EPT][NCOL];
    #pragma unroll
    for (int i = 0; i < EPT; ++i) {
        if (i < nv) {
            const float4 v = *reinterpret_cast<const float4*>(
                x + colbase + (size_t)(base_row + i) * C_COLS);
            const uint32_t w[4] = {__float_as_uint(v.x), __float_as_uint(v.y),
                                   __float_as_uint(v.z), __float_as_uint(v.w)};
            #pragma unroll
            for (int j = 0; j < NCOL; ++j)
                u[i][j] = w[j] ^ ((w[j] >> 31) ? 0xFFFFFFFFu : 0x80000000u);
        } else {
            #pragma unroll
            for (int j = 0; j < NCOL; ++j) u[i][j] = 0u;
        }
        // Pin in VGPRs: forbids the compiler from rematerializing the global
        // loads per radix pass (round-1 evidence: VGPR=52 < 64 live values,
        // FETCH 3.2x ideal).
        #pragma unroll
        for (int j = 0; j < NCOL; ++j) asm("" : "+v"(u[i][j]));
    }

    uint32_t thr[NCOL], tneed[NCOL];

    if (k > 0) {
        // ---- Radix-select the k-th largest, per column ----
        #pragma unroll
        for (int j = 0; j < NCOL; ++j) {
            uint32_t prefix = 0u, pmask = 0u, rem = (uint32_t)k;
            for (int pass = 0; pass < 4; ++pass) {
                const int shift = 24 - 8 * pass;
                #pragma unroll
                for (int z = 0; z < NSUB; ++z) hist[t * NSUB + z] = 0u;
                __syncthreads();
                const uint32_t sub = (uint32_t)(t & (NSUB - 1));
                #pragma unroll
                for (int i = 0; i < EPT; ++i) {
                    if (i < nv) {
                        const uint32_t ui = u[i][j];
                        if ((ui & pmask) == prefix)
                            atomicAdd(&hist[((ui >> shift) & 255u) * NSUB + sub], 1u);
                    }
                }
                __syncthreads();
                uint32_t cb = 0;
                #pragma unroll
                for (int z = 0; z < NSUB; ++z) cb += hist[t * NSUB + z];
                scanbuf[t] = cb;    // scanbuf[bin] = count
                __syncthreads();
                if (wid == 0) {
                    // lane l owns bins 255-4l .. 252-4l (descending)
                    uint32_t c4[4], loc[4], s = 0;
                    #pragma unroll
                    for (int q = 0; q < 4; ++q) {
                        c4[q]  = scanbuf[255 - 4 * lane - q];
                        loc[q] = s;
                        s += c4[q];
                    }
                    uint32_t incl = s;   // inclusive scan over lanes
                    #pragma unroll
                    for (int off = 1; off < 64; off <<= 1) {
                        const uint32_t nb = __shfl_up(incl, (unsigned)off, 64);
                        if (lane >= off) incl += nb;
                    }
                    const uint32_t gexcl = incl - s;
                    #pragma unroll
                    for (int q = 0; q < 4; ++q) {
                        const uint32_t sbb = gexcl + loc[q]; // #elems in higher bins
                        if (sbb < rem && sbb + c4[q] >= rem) {   // unique crossing
                            sh_sel = (uint32_t)(255 - 4 * lane - q);
                            sh_rem = rem - sbb;
                        }
                    }
                }
                __syncthreads();
                prefix |= sh_sel << shift;
                pmask  |= 0xFFu << shift;
                rem = sh_rem;
                __syncthreads();   // protect sh_*/hist reuse
            }
            thr[j]   = prefix;   // exact k-th largest value (as sortable uint)
            tneed[j] = rem;      // how many ties (==thr) to keep, in row order
        }

        // ---- Keep + compacted positions + write ----
        #pragma unroll
        for (int j = 0; j < NCOL; ++j) {
            const uint32_t th = thr[j], tn = tneed[j];
            uint32_t gt = 0, eq = 0;
            #pragma unroll
            for (int i = 0; i < EPT; ++i) {
                if (i < nv) {
                    gt += (u[i][j] > th) ? 1u : 0u;
                    eq += (u[i][j] == th) ? 1u : 0u;
                }
            }
            const uint32_t mine = (gt << 16) | eq;  // totals <= 4096, no carry
            uint32_t incl = mine;
            #pragma unroll
            for (int off = 1; off < 64; off <<= 1) {
                const uint32_t nb = __shfl_up(incl, (unsigned)off, 64);
                if (lane >= off) incl += nb;
            }
            if (lane == 63) wsum[wid] = incl;
            __syncthreads();
            uint32_t woff = 0;
            for (int w = 0; w < wid; ++w) woff += wsum[w];
            const uint32_t excl = incl + woff - mine;
            uint32_t g = excl >> 16;       // kept-gt strictly before my rows
            uint32_t e = excl & 0xFFFFu;   // eq strictly before my rows
            #pragma unroll
            for (int i = 0; i < EPT; ++i) {
                if (i < nv) {
                    const uint32_t ui = u[i][j];
                    const bool isgt = ui > th;
                    const bool iseq = (ui == th);
                    if (isgt || (iseq && e < tn)) {
                        const uint32_t pos = g + (e < tn ? e : tn);
                        const uint32_t bits =
                            ui ^ ((ui >> 31) ? 0x80000000u : 0xFFFFFFFFu);
                        if (MODE == 0) {
                            // dense block-local slab: ws[lin][pos][j]
                            ws[(size_t)lin * (T_ROWS * NCOL) +
                               (size_t)pos * NCOL + (size_t)j] = __uint_as_float(bits);
                        } else {
                            out[colbase + (size_t)pos * C_COLS + (size_t)j] =
                                __uint_as_float(bits);
                        }
                    }
                    g += isgt ? 1u : 0u;
                    e += iseq ? 1u : 0u;
                }
            }
            __syncthreads();   // wsum/scan reuse
        }
    }

    if (MODE == 1) {
        // ---- Zero-fill rows [k, T) ----
        for (int r = k + t; r < T_ROWS; r += BLOCK) {
            const float4 z = make_float4(0.f, 0.f, 0.f, 0.f);
            *reinterpret_cast<float4*>(out + colbase + (size_t)r * C_COLS) = z;
        }
    }

    // ---- Output 1: pool_result_ranges (k per batch), as float32 ----
    if (cg == 0 && t == 0)
        out[NTOT + (size_t)b] = (float)k;
}

// K2: transpose ws[b][cg][pos][4] -> out[b][pos][c] (coalesced both sides)
// and zero-fill rows >= k. 64-pos x 256-col tiles through a 64KB LDS tile.
__global__ __launch_bounds__(BLOCK)
void kmax_transpose_kernel(const float* __restrict__ ws,
                           const int*   __restrict__ lengths,
                           const int*   __restrict__ pool_ranges,
                           const int*   __restrict__ p_top_k,
                           const int*   __restrict__ p_layer,
                           const int*   __restrict__ p_total,
                           float*       __restrict__ out)
{
    extern __shared__ float4 tile_s[];   // [64 cg][64 pos] xor-swizzled, 64 KB

    const int bid  = blockIdx.x;
    const int b    = bid >> 6;
    const int tile = bid & 63;
    const int pos0 = tile * 64;

    int pr;
    const int k = compute_k(lengths, pool_ranges, p_top_k, p_layer, p_total, b, &pr);

    const int t = threadIdx.x;
    const int w = t >> 6;
    const int l = t & 63;
    const float4 z4 = make_float4(0.f, 0.f, 0.f, 0.f);
    float4* out4 = reinterpret_cast<float4*>(out);

    if (pos0 < k) {
        const float4* ws4 = reinterpret_cast<const float4*>(ws);
        #pragma unroll
        for (int cgi = 0; cgi < 16; ++cgi) {
            const int cg = cgi * 4 + w;
            // 64 lanes x 16B contiguous = 1KB coalesced read per (warp,cg)
            tile_s[cg * 64 + (l ^ cg)] =
                ws4[(size_t)(b * NGROUP + cg) * T_ROWS + (size_t)(pos0 + l)];
        }
        __syncthreads();
        #pragma unroll
        for (int it = 0; it < 16; ++it) {
            const int idx = it * BLOCK + t;
            const int row = idx >> 6;       // constant per wave
            const int cq  = idx & 63;       // lane -> consecutive col-quads
            const int pos = pos0 + row;
            const float4 v = (pos < k) ? tile_s[cq * 64 + (row ^ cq)] : z4;
            out4[((size_t)b * T_ROWS + (size_t)pos) * (C_COLS / 4) + (size_t)cq] = v;
        }
    } else {
        #pragma unroll
        for (int it = 0; it < 16; ++it) {
            const int idx = it * BLOCK + t;
            const int row = idx >> 6;
            const int cq  = idx & 63;
            out4[((size_t)b * T_ROWS + (size_t)(pos0 + row)) * (C_COLS / 4) +
                 (size_t)cq] = z4;
        }
    }
}

extern "C" void kernel_launch(void* const* d_in, const int* in_sizes, int n_in,
                              void* d_out, int out_size, void* d_ws, size_t ws_size,
                              hipStream_t stream)
{
    const float* x            = (const float*)d_in[0];
    const int*   lengths      = (const int*)d_in[1];
    const int*   pool_ranges  = (const int*)d_in[2];
    const int*   top_k        = (const int*)d_in[3];
    const int*   layer        = (const int*)d_in[4];
    const int*   total_layers = (const int*)d_in[5];
    float*       out          = (float*)d_out;
    float*       ws           = (float*)d_ws;

    const size_t ws_need = (size_t)NBLK * T_ROWS * NCOL * sizeof(float); // 64 MiB

    dim3 grid(NBLK);
    dim3 block(BLOCK);
    if (ws_size >= ws_need) {
        hipLaunchKernelGGL(kmax_select_kernel<0>, grid, block, 0, stream,
                           x, lengths, pool_ranges, top_k, layer, total_layers, out, ws);
        hipLaunchKernelGGL(kmax_transpose_kernel, grid, block, 65536, stream,
                           ws, lengths, pool_ranges, top_k, layer, total_layers, out);
    } else {
        hipLaunchKernelGGL(kmax_select_kernel<1>, grid, block, 0, stream,
                           x, lengths, pool_ranges, top_k, layer, total_layers, out, ws);
    }
}

// Round 3
// 112.298 us; speedup vs baseline: 1.9891x; 1.0593x over previous
//
#include <hip/hip_runtime.h>
#include <stdint.h>

// DynamicMaxPool: per-column k-max pooling with order preservation.
// x: [B=16, T=4096, C=256] f32. For each (b,c): keep the k largest of the
// first pr rows (ties -> lower row index, matching stable argsort), compacted
// to rows 0..k-1 in original row order; rows k..T-1 zero. k is per-BATCH, so
// the output is a dense [k,C] slab + zeros -> two-phase: dense select into ws
// (block-local layout, fully-dirtied lines), then coalesced transpose+zerofill.
// Output 1: k per batch (float32).
//
// Round-2 evidence: select kernel was latency/serialization-bound (VALUBusy
// 17%, FETCH 27MB L3-resident, VGPR=52 => u[] spilled to scratch). This
// version: 512 thr/blk (EPT=8, fits VGPR), all 4 columns' histograms built
// concurrently (12 barriers total instead of ~70), scans on 4 parallel waves.

constexpr int T_ROWS = 4096;
constexpr int C_COLS = 256;
constexpr int NBATCH = 16;
constexpr int SBLOCK = 512;              // select-kernel block
constexpr int EPT    = T_ROWS / SBLOCK;  // 8 rows per thread
constexpr int NCOL   = 4;                // columns per select-block
constexpr int NSUB   = 4;                // histogram sub-counters per bin
constexpr int HPAD   = 8;                // words: shift each col's banks
constexpr int HSTRIDE = 256 * NSUB + HPAD;
constexpr int NGROUP = C_COLS / NCOL;    // 64 column-groups per batch
constexpr int NBLK   = NBATCH * NGROUP;  // 1024 select blocks
constexpr size_t NTOT = (size_t)NBATCH * T_ROWS * C_COLS;

__device__ __forceinline__ int compute_k(const int* lengths, const int* pool_ranges,
                                         const int* p_top_k, const int* p_layer,
                                         const int* p_total, int b, int* pr_out)
{
    int pr = pool_ranges[b];
    pr = pr < 0 ? 0 : (pr > T_ROWS ? T_ROWS : pr);
    const int len   = lengths[b];
    const int top_k = p_top_k[0];
    const int tot   = p_total[0];
    const int num   = tot - p_layer[0];
    int k = (num * len + tot - 1) / tot;   // ceil, positive ints
    if (k < top_k) k = top_k;
    if (k > pr)    k = pr;
    *pr_out = pr;
    return k;
}

// MODE 0: write dense per-block slab into ws (K2 transposes). MODE 1: direct
// scattered writes to out + zero-fill (fallback when ws too small).
template<int MODE>
__global__ __launch_bounds__(SBLOCK)
void kmax_select_kernel(const float* __restrict__ x,
                        const int*   __restrict__ lengths,
                        const int*   __restrict__ pool_ranges,
                        const int*   __restrict__ p_top_k,
                        const int*   __restrict__ p_layer,
                        const int*   __restrict__ p_total,
                        float*       __restrict__ out,
                        float*       __restrict__ ws)
{
    __shared__ uint32_t hist[NCOL * HSTRIDE];        // ~16.5 KB, bank-padded
    __shared__ uint32_t wsum[SBLOCK / 64][NCOL];
    __shared__ uint32_t sh_sel[NCOL], sh_rem[NCOL];

    // XCD-chunked swizzle: adjacent lin (adjacent cg) -> same XCD, adjacent
    // issue slot -> 4 blocks sharing each 64B x line co-reside in one L2.
    const int bid  = blockIdx.x;
    const int lin  = (bid & 7) * (NBLK / 8) + (bid >> 3);
    const int b    = lin / NGROUP;
    const int cg   = lin % NGROUP;
    const int c0   = cg * NCOL;
    const int t    = threadIdx.x;
    const int lane = t & 63;
    const int wid  = t >> 6;

    int pr;
    const int k = compute_k(lengths, pool_ranges, p_top_k, p_layer, p_total, b, &pr);

    const int base_row = t * EPT;
    int nv = pr - base_row;                // valid rows owned by this thread
    nv = nv < 0 ? 0 : (nv > EPT ? EPT : nv);

    const size_t colbase = (size_t)b * T_ROWS * C_COLS + (size_t)c0;

    // ---- Load once: 8 rows x 4 cols per thread, as sortable uints ----
    // Rows are always in-bounds (pr only gates validity); load unconditionally
    // and mask invalid rows to 0 (< any finite value's sortable key).
    uint32_t u[EPT][NCOL];
    #pragma unroll
    for (int i = 0; i < EPT; ++i) {
        const float4 v = *reinterpret_cast<const float4*>(
            x + colbase + (size_t)(base_row + i) * C_COLS);
        const uint32_t w[4] = {__float_as_uint(v.x), __float_as_uint(v.y),
                               __float_as_uint(v.z), __float_as_uint(v.w)};
        const bool valid = (i < nv);
        #pragma unroll
        for (int j = 0; j < NCOL; ++j) {
            u[i][j] = valid ? (w[j] ^ ((w[j] >> 31) ? 0xFFFFFFFFu : 0x80000000u))
                            : 0u;
            asm("" : "+v"(u[i][j]));   // pin in VGPR (no remat / no scratch)
        }
    }

    uint32_t prefix[NCOL] = {0u, 0u, 0u, 0u};
    uint32_t rem[NCOL];
    #pragma unroll
    for (int j = 0; j < NCOL; ++j) rem[j] = (uint32_t)k;

    if (k > 0) {
        // ---- Radix-select the k-th largest, all 4 columns concurrently ----
        uint32_t pmask = 0u;
        const uint32_t sub = (uint32_t)(t & (NSUB - 1));
        for (int pass = 0; pass < 4; ++pass) {
            const int shift = 24 - 8 * pass;
            for (int z = t; z < NCOL * HSTRIDE; z += SBLOCK) hist[z] = 0u;
            __syncthreads();
            #pragma unroll
            for (int j = 0; j < NCOL; ++j) {
                #pragma unroll
                for (int i = 0; i < EPT; ++i) {
                    if (i < nv) {
                        const uint32_t ui = u[i][j];
                        if ((ui & pmask) == prefix[j])
                            atomicAdd(&hist[j * HSTRIDE +
                                            ((ui >> shift) & 255u) * NSUB + sub], 1u);
                    }
                }
            }
            __syncthreads();
            if (wid < NCOL) {
                const int j = wid;          // wave j scans column j's bins
                uint32_t c4[4], loc[4], s = 0;
                #pragma unroll
                for (int q = 0; q < 4; ++q) {
                    const int bin = 255 - 4 * lane - q;   // descending bins
                    uint32_t cnt = 0;
                    #pragma unroll
                    for (int z = 0; z < NSUB; ++z)
                        cnt += hist[j * HSTRIDE + bin * NSUB + z];
                    c4[q]  = cnt;
                    loc[q] = s;
                    s += cnt;
                }
                uint32_t incl = s;   // inclusive scan over lanes
                #pragma unroll
                for (int off = 1; off < 64; off <<= 1) {
                    const uint32_t nb = __shfl_up(incl, (unsigned)off, 64);
                    if (lane >= off) incl += nb;
                }
                const uint32_t gexcl = incl - s;
                const uint32_t rj = rem[j];
                #pragma unroll
                for (int q = 0; q < 4; ++q) {
                    const uint32_t sbb = gexcl + loc[q]; // #elems in higher bins
                    if (sbb < rj && sbb + c4[q] >= rj) {   // unique crossing
                        sh_sel[j] = (uint32_t)(255 - 4 * lane - q);
                        sh_rem[j] = rj - sbb;
                    }
                }
            }
            __syncthreads();
            #pragma unroll
            for (int j = 0; j < NCOL; ++j) {
                prefix[j] |= sh_sel[j] << shift;
                rem[j]     = sh_rem[j];
            }
            pmask |= 0xFFu << shift;
            // next-pass hist zeroing is ordered by the barrier at loop top
        }

        // ---- Keep + compacted positions + write (all 4 cols, 1 barrier) ----
        uint32_t mine[NCOL], incl[NCOL];
        #pragma unroll
        for (int j = 0; j < NCOL; ++j) {
            uint32_t gt = 0, eq = 0;
            #pragma unroll
            for (int i = 0; i < EPT; ++i) {
                if (i < nv) {
                    gt += (u[i][j] > prefix[j]) ? 1u : 0u;
                    eq += (u[i][j] == prefix[j]) ? 1u : 0u;
                }
            }
            mine[j] = (gt << 16) | eq;  // totals <= 4096, no carry
            uint32_t v = mine[j];
            #pragma unroll
            for (int off = 1; off < 64; off <<= 1) {
                const uint32_t nb = __shfl_up(v, (unsigned)off, 64);
                if (lane >= off) v += nb;
            }
            incl[j] = v;
            if (lane == 63) wsum[wid][j] = v;
        }
        __syncthreads();
        #pragma unroll
        for (int j = 0; j < NCOL; ++j) {
            uint32_t woff = 0;
            for (int w = 0; w < wid; ++w) woff += wsum[w][j];
            const uint32_t excl = incl[j] + woff - mine[j];
            uint32_t g = excl >> 16;       // kept-gt strictly before my rows
            uint32_t e = excl & 0xFFFFu;   // eq strictly before my rows
            const uint32_t th = prefix[j], tn = rem[j];
            #pragma unroll
            for (int i = 0; i < EPT; ++i) {
                if (i < nv) {
                    const uint32_t ui = u[i][j];
                    const bool isgt = ui > th;
                    const bool iseq = (ui == th);
                    if (isgt || (iseq && e < tn)) {
                        const uint32_t pos = g + (e < tn ? e : tn);
                        const uint32_t bits =
                            ui ^ ((ui >> 31) ? 0x80000000u : 0xFFFFFFFFu);
                        if (MODE == 0) {
                            // dense block-local slab: ws[lin][pos][j]
                            ws[(size_t)lin * (T_ROWS * NCOL) +
                               (size_t)pos * NCOL + (size_t)j] = __uint_as_float(bits);
                        } else {
                            out[colbase + (size_t)pos * C_COLS + (size_t)j] =
                                __uint_as_float(bits);
                        }
                    }
                    g += isgt ? 1u : 0u;
                    e += iseq ? 1u : 0u;
                }
            }
        }
    }

    if (MODE == 1) {
        // ---- Zero-fill rows [k, T) ----
        for (int r = k + t; r < T_ROWS; r += SBLOCK) {
            const float4 z = make_float4(0.f, 0.f, 0.f, 0.f);
            *reinterpret_cast<float4*>(out + colbase + (size_t)r * C_COLS) = z;
        }
    }

    // ---- Output 1: pool_result_ranges (k per batch), as float32 ----
    if (cg == 0 && t == 0)
        out[NTOT + (size_t)b] = (float)k;
}

// K2: transpose ws[b][cg][pos][4] -> out[b][pos][c] (coalesced both sides)
// and zero-fill rows >= k. 64-pos x 256-col tiles through a 64KB LDS tile.
constexpr int TBLOCK = 256;

__global__ __launch_bounds__(TBLOCK)
void kmax_transpose_kernel(const float* __restrict__ ws,
                           const int*   __restrict__ lengths,
                           const int*   __restrict__ pool_ranges,
                           const int*   __restrict__ p_top_k,
                           const int*   __restrict__ p_layer,
                           const int*   __restrict__ p_total,
                           float*       __restrict__ out)
{
    extern __shared__ float4 tile_s[];   // [64 cg][64 pos] xor-swizzled, 64 KB

    const int bid  = blockIdx.x;
    const int b    = bid >> 6;
    const int tile = bid & 63;
    const int pos0 = tile * 64;

    int pr;
    const int k = compute_k(lengths, pool_ranges, p_top_k, p_layer, p_total, b, &pr);

    const int t = threadIdx.x;
    const int w = t >> 6;
    const int l = t & 63;
    const float4 z4 = make_float4(0.f, 0.f, 0.f, 0.f);
    float4* out4 = reinterpret_cast<float4*>(out);

    if (pos0 < k) {
        const float4* ws4 = reinterpret_cast<const float4*>(ws);
        #pragma unroll
        for (int cgi = 0; cgi < 16; ++cgi) {
            const int cg = cgi * 4 + w;
            // 64 lanes x 16B contiguous = 1KB coalesced read per (warp,cg)
            tile_s[cg * 64 + (l ^ cg)] =
                ws4[(size_t)(b * NGROUP + cg) * T_ROWS + (size_t)(pos0 + l)];
        }
        __syncthreads();
        #pragma unroll
        for (int it = 0; it < 16; ++it) {
            const int idx = it * TBLOCK + t;
            const int row = idx >> 6;       // constant per wave
            const int cq  = idx & 63;       // lane -> consecutive col-quads
            const int pos = pos0 + row;
            const float4 v = (pos < k) ? tile_s[cq * 64 + (row ^ cq)] : z4;
            out4[((size_t)b * T_ROWS + (size_t)pos) * (C_COLS / 4) + (size_t)cq] = v;
        }
    } else {
        #pragma unroll
        for (int it = 0; it < 16; ++it) {
            const int idx = it * TBLOCK + t;
            const int row = idx >> 6;
            const int cq  = idx & 63;
            out4[((size_t)b * T_ROWS + (size_t)(pos0 + row)) * (C_COLS / 4) +
                 (size_t)cq] = z4;
        }
    }
}

extern "C" void kernel_launch(void* const* d_in, const int* in_sizes, int n_in,
                              void* d_out, int out_size, void* d_ws, size_t ws_size,
                              hipStream_t stream)
{
    const float* x            = (const float*)d_in[0];
    const int*   lengths      = (const int*)d_in[1];
    const int*   pool_ranges  = (const int*)d_in[2];
    const int*   top_k        = (const int*)d_in[3];
    const int*   layer        = (const int*)d_in[4];
    const int*   total_layers = (const int*)d_in[5];
    float*       out          = (float*)d_out;
    float*       ws           = (float*)d_ws;

    const size_t ws_need = (size_t)NBLK * T_ROWS * NCOL * sizeof(float); // 64 MiB

    if (ws_size >= ws_need) {
        hipLaunchKernelGGL(kmax_select_kernel<0>, dim3(NBLK), dim3(SBLOCK), 0, stream,
                           x, lengths, pool_ranges, top_k, layer, total_layers, out, ws);
        hipLaunchKernelGGL(kmax_transpose_kernel, dim3(NBLK), dim3(TBLOCK), 65536, stream,
                           ws, lengths, pool_ranges, top_k, layer, total_layers, out);
    } else {
        hipLaunchKernelGGL(kmax_select_kernel<1>, dim3(NBLK), dim3(SBLOCK), 0, stream,
                           x, lengths, pool_ranges, top_k, layer, total_layers, out, ws);
    }
}

// Round 4
// 92.267 us; speedup vs baseline: 2.4209x; 1.2171x over previous
//
#include <hip/hip_runtime.h>
#include <stdint.h>

// DynamicMaxPool: per-column k-max pooling with order preservation.
// x: [B=16, T=4096, C=256] f32. For each (b,c): keep the k largest of the
// first pr rows (ties -> lower row index, stable), compacted to rows 0..k-1
// in original row order; rows k..T-1 zero. k is per-batch.
// Two-phase: dense select into ws (block-local layout), coalesced transpose.
//
// Round-3 evidence: block-wide radix select was serialization-bound
// (VALUBusy 21%, ~13 barriers, scans on half the waves). This version:
// one WAVE per column -> select/keep phases are wave-synchronous with ZERO
// block barriers; 16-column blocks give fully-coalesced 64B-line loads,
// staged via double-buffered LDS (1 barrier per chunk, 8 total).

constexpr int T_ROWS = 4096;
constexpr int C_COLS = 256;
constexpr int NBATCH = 16;
constexpr int SBLOCK = 1024;             // 16 waves, one column each
constexpr int SWAVES = 16;
constexpr int NCHUNK = 8;
constexpr int CROWS  = 512;              // rows per staged chunk
constexpr int CPAD   = 17;               // 16 cols + 1 pad (odd -> ~2-way banks)
constexpr int EPL    = 64;               // values per lane (T_ROWS/64)
constexpr int NSUB   = 2;                // hist sub-counters (by lane parity)
constexpr int NGB    = C_COLS / SWAVES;  // 16 col-blocks per batch
constexpr int NBLK   = NBATCH * NGB;     // 256 select blocks
constexpr size_t NTOT = (size_t)NBATCH * T_ROWS * C_COLS;

__device__ __forceinline__ int compute_k(const int* lengths, const int* pool_ranges,
                                         const int* p_top_k, const int* p_layer,
                                         const int* p_total, int b, int* pr_out)
{
    int pr = pool_ranges[b];
    pr = pr < 0 ? 0 : (pr > T_ROWS ? T_ROWS : pr);
    const int len   = lengths[b];
    const int top_k = p_top_k[0];
    const int tot   = p_total[0];
    const int num   = tot - p_layer[0];
    int k = (num * len + tot - 1) / tot;   // ceil, positive ints
    if (k < top_k) k = top_k;
    if (k > pr)    k = pr;
    *pr_out = pr;
    return k;
}

// MODE 0: dense per-column slab into ws (K2 transposes). MODE 1: direct
// scattered writes to out + zero-fill (fallback when ws too small).
template<int MODE>
__global__ __launch_bounds__(SBLOCK, 4)
void kmax_select_kernel(const float* __restrict__ x,
                        const int*   __restrict__ lengths,
                        const int*   __restrict__ pool_ranges,
                        const int*   __restrict__ p_top_k,
                        const int*   __restrict__ p_layer,
                        const int*   __restrict__ p_total,
                        float*       __restrict__ out,
                        float*       __restrict__ ws)
{
    __shared__ float    stage[2][CROWS][CPAD];       // 69,632 B
    __shared__ uint32_t hist[SWAVES][256 * NSUB];    // 32,768 B (wave-private)

    const int t    = threadIdx.x;
    const int lane = t & 63;
    const int wid  = t >> 6;
    const int bid  = blockIdx.x;
    const int b    = bid >> 4;           // 16 blocks per batch
    const int cgrp = bid & 15;
    const int c0   = cgrp * 16;
    const int c    = c0 + wid;           // this wave's column

    int pr;
    const int k = compute_k(lengths, pool_ranges, p_top_k, p_layer, p_total, b, &pr);

    // ---- issue ALL global loads up front (fully coalesced: lanes 0..3 cover
    //      one 64B line; 16 float4 per thread = the block's whole strip) ----
    const int rq = t >> 2;               // 0..255: row within half-chunk
    const int q  = t & 3;                // which float4 of the 16-col strip
    const float* xb = x + (size_t)b * T_ROWS * C_COLS + (size_t)c0 + (size_t)(q * 4);
    float4 ga[NCHUNK], gb[NCHUNK];
    #pragma unroll
    for (int ci = 0; ci < NCHUNK; ++ci) {
        ga[ci] = *reinterpret_cast<const float4*>(xb + (size_t)(ci * CROWS + rq) * C_COLS);
        gb[ci] = *reinterpret_cast<const float4*>(xb + (size_t)(ci * CROWS + 256 + rq) * C_COLS);
    }

    // ---- stage chunks through LDS; transpose to per-wave column registers.
    //      One barrier per chunk: reads of chunk ci are provably complete
    //      before any wave's stores of chunk ci+2 (same buffer), because each
    //      wave consumes its reads (into u[]) before reaching barrier ci+1. --
    uint32_t u[EPL];                      // 64 sortable keys, lane-strided rows
    #pragma unroll
    for (int ci = 0; ci < NCHUNK; ++ci) {
        const int buf = ci & 1;
        stage[buf][rq      ][q * 4 + 0] = ga[ci].x;
        stage[buf][rq      ][q * 4 + 1] = ga[ci].y;
        stage[buf][rq      ][q * 4 + 2] = ga[ci].z;
        stage[buf][rq      ][q * 4 + 3] = ga[ci].w;
        stage[buf][rq + 256][q * 4 + 0] = gb[ci].x;
        stage[buf][rq + 256][q * 4 + 1] = gb[ci].y;
        stage[buf][rq + 256][q * 4 + 2] = gb[ci].z;
        stage[buf][rq + 256][q * 4 + 3] = gb[ci].w;
        __syncthreads();
        #pragma unroll
        for (int mm = 0; mm < 8; ++mm) {
            const int m = ci * 8 + mm;            // global row = m*64 + lane
            const uint32_t w = __float_as_uint(stage[buf][mm * 64 + lane][wid]);
            const uint32_t key = w ^ ((w >> 31) ? 0xFFFFFFFFu : 0x80000000u);
            u[m] = ((m * 64 + lane) < pr) ? key : 0u;
            asm("" : "+v"(u[m]));                 // pin in VGPR (no remat)
        }
    }

    // ---- wave-local radix select of the k-th largest (zero barriers) ----
    uint32_t prefix = 0u, pmask = 0u, rem = (uint32_t)k;
    if (k > 0) {
        for (int pass = 0; pass < 4; ++pass) {
            const int shift = 24 - 8 * pass;
            #pragma unroll
            for (int z = 0; z < (256 * NSUB) / 64; ++z)
                hist[wid][z * 64 + lane] = 0u;
            #pragma unroll
            for (int m = 0; m < EPL; ++m) {
                const uint32_t ui = u[m];
                if ((ui & pmask) == prefix)
                    atomicAdd(&hist[wid][((ui >> shift) & 255u) * NSUB + (lane & (NSUB - 1))], 1u);
            }
            // scan 256 bins descending: lane owns positions lane*4..lane*4+3
            uint32_t c4[4], loc[4], s = 0;
            #pragma unroll
            for (int qq = 0; qq < 4; ++qq) {
                const int bin = 255 - (lane * 4 + qq);
                uint32_t cnt = 0;
                #pragma unroll
                for (int z = 0; z < NSUB; ++z) cnt += hist[wid][bin * NSUB + z];
                c4[qq] = cnt; loc[qq] = s; s += cnt;
            }
            uint32_t incl = s;
            #pragma unroll
            for (int off = 1; off < 64; off <<= 1) {
                const uint32_t nb = __shfl_up(incl, (unsigned)off, 64);
                if (lane >= off) incl += nb;
            }
            const uint32_t gexcl = incl - s;
            uint32_t sel = 0, nrem = 0;
            bool found = false;
            #pragma unroll
            for (int qq = 0; qq < 4; ++qq) {
                const uint32_t sbb = gexcl + loc[qq];   // #elems in higher bins
                if (sbb < rem && sbb + c4[qq] >= rem) { // unique crossing
                    sel  = (uint32_t)(255 - (lane * 4 + qq));
                    nrem = rem - sbb;
                    found = true;
                }
            }
            const unsigned long long fm = __ballot(found);
            const int src = __ffsll((unsigned long long)fm) - 1;
            sel  = __shfl(sel,  src, 64);
            nrem = __shfl(nrem, src, 64);
            prefix |= sel << shift;
            pmask  |= 0xFFu << shift;
            rem = nrem;
        }

        // ---- keep + compact via ballot scans (wave-local, no LDS) ----
        const uint32_t th = prefix, tn = rem;
        const unsigned long long ltm = (1ull << lane) - 1ull;
        uint32_t G = 0, E = 0;           // kept-gt / eq totals in rows so far
        const size_t wsbase  = (size_t)(b * 64 + (c >> 2)) * (size_t)(T_ROWS * 4) + (size_t)(c & 3);
        const size_t outbase = (size_t)b * T_ROWS * C_COLS + (size_t)c;
        #pragma unroll
        for (int m = 0; m < EPL; ++m) {
            const int row = m * 64 + lane;
            const uint32_t ui = u[m];
            const bool v    = row < pr;
            const bool mygt = v && (ui > th);
            const bool myeq = v && (ui == th);
            const unsigned long long gm = __ballot(mygt);
            const unsigned long long em = __ballot(myeq);
            const uint32_t my_g = G + (uint32_t)__popcll(gm & ltm);
            const uint32_t my_e = E + (uint32_t)__popcll(em & ltm);
            if (mygt || (myeq && my_e < tn)) {
                const uint32_t pos  = my_g + (my_e < tn ? my_e : tn);
                const uint32_t bits = ui ^ ((ui >> 31) ? 0x80000000u : 0xFFFFFFFFu);
                if (MODE == 0)
                    ws[wsbase + (size_t)pos * 4] = __uint_as_float(bits);
                else
                    out[outbase + (size_t)pos * C_COLS] = __uint_as_float(bits);
            }
            G += (uint32_t)__popcll(gm);
            E += (uint32_t)__popcll(em);
        }
    }

    if (MODE == 1) {
        // zero-fill rows [k, T) of this wave's column (fallback path only)
        const size_t outbase = (size_t)b * T_ROWS * C_COLS + (size_t)c;
        for (int r = k + lane; r < T_ROWS; r += 64)
            out[outbase + (size_t)r * C_COLS] = 0.f;
    }

    // ---- Output 1: pool_result_ranges (k per batch), as float32 ----
    if (cgrp == 0 && t == 0)
        out[NTOT + (size_t)b] = (float)k;
}

// K2: transpose ws[b][cg][pos][4] -> out[b][pos][c] (coalesced both sides)
// and zero-fill rows >= k. 64-pos x 256-col tiles through a 64KB LDS tile.
constexpr int TBLOCK = 256;

__global__ __launch_bounds__(TBLOCK)
void kmax_transpose_kernel(const float* __restrict__ ws,
                           const int*   __restrict__ lengths,
                           const int*   __restrict__ pool_ranges,
                           const int*   __restrict__ p_top_k,
                           const int*   __restrict__ p_layer,
                           const int*   __restrict__ p_total,
                           float*       __restrict__ out)
{
    extern __shared__ float4 tile_s[];   // [64 cg][64 pos] xor-swizzled, 64 KB

    const int bid  = blockIdx.x;
    const int b    = bid >> 6;
    const int tile = bid & 63;
    const int pos0 = tile * 64;

    int pr;
    const int k = compute_k(lengths, pool_ranges, p_top_k, p_layer, p_total, b, &pr);

    const int t = threadIdx.x;
    const int w = t >> 6;
    const int l = t & 63;
    const float4 z4 = make_float4(0.f, 0.f, 0.f, 0.f);
    float4* out4 = reinterpret_cast<float4*>(out);

    if (pos0 < k) {
        const float4* ws4 = reinterpret_cast<const float4*>(ws);
        #pragma unroll
        for (int cgi = 0; cgi < 16; ++cgi) {
            const int cg = cgi * 4 + w;
            // 64 lanes x 16B contiguous = 1KB coalesced read per (warp,cg)
            tile_s[cg * 64 + (l ^ cg)] =
                ws4[(size_t)(b * 64 + cg) * T_ROWS + (size_t)(pos0 + l)];
        }
        __syncthreads();
        #pragma unroll
        for (int it = 0; it < 16; ++it) {
            const int idx = it * TBLOCK + t;
            const int row = idx >> 6;       // constant per wave
            const int cq  = idx & 63;       // lane -> consecutive col-quads
            const int pos = pos0 + row;
            const float4 v = (pos < k) ? tile_s[cq * 64 + (row ^ cq)] : z4;
            out4[((size_t)b * T_ROWS + (size_t)pos) * (C_COLS / 4) + (size_t)cq] = v;
        }
    } else {
        #pragma unroll
        for (int it = 0; it < 16; ++it) {
            const int idx = it * TBLOCK + t;
            const int row = idx >> 6;
            const int cq  = idx & 63;
            out4[((size_t)b * T_ROWS + (size_t)(pos0 + row)) * (C_COLS / 4) +
                 (size_t)cq] = z4;
        }
    }
}

extern "C" void kernel_launch(void* const* d_in, const int* in_sizes, int n_in,
                              void* d_out, int out_size, void* d_ws, size_t ws_size,
                              hipStream_t stream)
{
    const float* x            = (const float*)d_in[0];
    const int*   lengths      = (const int*)d_in[1];
    const int*   pool_ranges  = (const int*)d_in[2];
    const int*   top_k        = (const int*)d_in[3];
    const int*   layer        = (const int*)d_in[4];
    const int*   total_layers = (const int*)d_in[5];
    float*       out          = (float*)d_out;
    float*       ws           = (float*)d_ws;

    const size_t ws_need = (size_t)NBATCH * 64 * T_ROWS * 4 * sizeof(float); // 64 MiB

    if (ws_size >= ws_need) {
        hipLaunchKernelGGL(kmax_select_kernel<0>, dim3(NBLK), dim3(SBLOCK), 0, stream,
                           x, lengths, pool_ranges, top_k, layer, total_layers, out, ws);
        hipLaunchKernelGGL(kmax_transpose_kernel, dim3(NBATCH * 64), dim3(TBLOCK), 65536, stream,
                           ws, lengths, pool_ranges, top_k, layer, total_layers, out);
    } else {
        hipLaunchKernelGGL(kmax_select_kernel<1>, dim3(NBLK), dim3(SBLOCK), 0, stream,
                           x, lengths, pool_ranges, top_k, layer, total_layers, out, ws);
    }
}